// Round 1
// baseline (82.075 us; speedup 1.0000x reference)
//
#include <hip/hip_runtime.h>
#include <math.h>

#define NUM_BINS 256
#define BATCH 16
#define PLANE_PIX (1024 * 1024)

__device__ __forceinline__ float sigmoidf_(float x) {
    return 1.0f / (1.0f + expf(-x));
}

// One block per channel (r,g,b). Computes:
//   a = sigmoid(src); a = cumsum(a, axis=1); a = (a - a.min()) / (a.max() - a.min())
// and writes curve[b][ch][bin] (layout [16][3][256]).
__global__ __launch_bounds__(256) void curves_kernel(
    const float* __restrict__ rr, const float* __restrict__ gr,
    const float* __restrict__ br, float* __restrict__ curve)
{
    const int ch = blockIdx.x;  // 0=r, 1=g, 2=b
    const float* src = (ch == 0) ? rr : (ch == 1) ? gr : br;

    __shared__ float s[BATCH][NUM_BINS];
    __shared__ float s_mn, s_inv;

    const int t = threadIdx.x;

    // load + sigmoid
    for (int i = t; i < BATCH * NUM_BINS; i += 256) {
        s[i >> 8][i & 255] = sigmoidf_(src[i]);
    }
    __syncthreads();

    // inclusive cumsum along bins: one wave per row, 4 rows in parallel.
    // Each lane owns 4 consecutive bins; wave-scan the lane sums.
    const int wave = t >> 6;
    const int lane = t & 63;
    for (int row = wave; row < BATCH; row += 4) {
        float v0 = s[row][lane * 4 + 0];
        float v1 = s[row][lane * 4 + 1];
        float v2 = s[row][lane * 4 + 2];
        float v3 = s[row][lane * 4 + 3];
        float p1 = v0 + v1;
        float p2 = p1 + v2;
        float p3 = p2 + v3;
        float sum = p3;
        #pragma unroll
        for (int d = 1; d < 64; d <<= 1) {
            float o = __shfl_up(sum, d, 64);
            if (lane >= d) sum += o;
        }
        const float off = sum - p3;  // exclusive prefix of this lane's chunk
        s[row][lane * 4 + 0] = off + v0;
        s[row][lane * 4 + 1] = off + p1;
        s[row][lane * 4 + 2] = off + p2;
        s[row][lane * 4 + 3] = off + p3;
    }
    __syncthreads();

    // Global min/max over the whole [16,256] tensor. Rows are monotone
    // non-decreasing (sigmoid > 0), so min is at bin 0, max at bin 255.
    if (t == 0) {
        float mn = s[0][0], mx = s[0][NUM_BINS - 1];
        for (int r = 1; r < BATCH; ++r) {
            mn = fminf(mn, s[r][0]);
            mx = fmaxf(mx, s[r][NUM_BINS - 1]);
        }
        s_mn = mn;
        s_inv = 1.0f / (mx - mn);
    }
    __syncthreads();

    const float mn = s_mn;
    const float inv = s_inv;
    for (int i = t; i < BATCH * NUM_BINS; i += 256) {
        const int row = i >> 8, col = i & 255;
        curve[(row * 3 + ch) * NUM_BINS + col] = (s[row][col] - mn) * inv;
    }
}

// blockIdx.y = plane (b*3 + c), 48 planes. Each plane: 1024*1024 f32 pixels.
// 256 blocks per plane, 256 threads, 4 x float4 per thread (16 px/thread).
__global__ __launch_bounds__(256) void lut_kernel(
    const float* __restrict__ img, const float* __restrict__ curve,
    float* __restrict__ out)
{
    __shared__ float lut[NUM_BINS];
    const int plane = blockIdx.y;
    lut[threadIdx.x] = curve[plane * NUM_BINS + threadIdx.x];
    __syncthreads();

    const size_t planeOff = (size_t)plane * PLANE_PIX;
    const float4* __restrict__ src = (const float4*)(img + planeOff);
    float4*       __restrict__ dst = (float4*)(out + planeOff);

    const int base = blockIdx.x * 1024 + threadIdx.x;
    #pragma unroll
    for (int k = 0; k < 4; ++k) {
        const int i = base + k * 256;
        const float4 v = src[i];
        float4 o;
        o.x = lut[(int)fminf(fmaxf(v.x * 255.0f, 0.0f), 255.0f)];
        o.y = lut[(int)fminf(fmaxf(v.y * 255.0f, 0.0f), 255.0f)];
        o.z = lut[(int)fminf(fmaxf(v.z * 255.0f, 0.0f), 255.0f)];
        o.w = lut[(int)fminf(fmaxf(v.w * 255.0f, 0.0f), 255.0f)];
        dst[i] = o;
    }
}

extern "C" void kernel_launch(void* const* d_in, const int* in_sizes, int n_in,
                              void* d_out, int out_size, void* d_ws, size_t ws_size,
                              hipStream_t stream) {
    const float* img = (const float*)d_in[0];
    const float* rr  = (const float*)d_in[1];
    const float* gr  = (const float*)d_in[2];
    const float* br  = (const float*)d_in[3];
    float* out   = (float*)d_out;
    float* curve = (float*)d_ws;  // 16*3*256 floats = 48 KiB scratch

    curves_kernel<<<dim3(3), dim3(256), 0, stream>>>(rr, gr, br, curve);
    lut_kernel<<<dim3(256, 48), dim3(256), 0, stream>>>(img, curve, out);
}

// Round 2
// 65.952 us; speedup vs baseline: 1.2445x; 1.2445x over previous
//
#include <hip/hip_runtime.h>
#include <math.h>

#define NUM_BINS 256
#define BATCH 16
#define PLANE_PIX (1024 * 1024)
#define VEC_PER_PLANE (PLANE_PIX / 4)   // 262144 float4 per plane
#define F4_PER_THREAD 8
#define BLOCKS_PER_PLANE (VEC_PER_PLANE / (256 * F4_PER_THREAD))  // 128

typedef float f32x4 __attribute__((ext_vector_type(4)));

__device__ __forceinline__ float sigmoidf_(float x) {
    return 1.0f / (1.0f + __expf(-x));
}

// Fused: each block (plane = blockIdx.y = b*3+c) first builds its own
// 256-entry LUT (sigmoid -> cumsum -> global per-channel min-max), then
// streams its slice of the plane through the LUT.
//   min over [16,256] cumsum = min_r cumsum[r][0]   (rows monotone, sigmoid>0)
//   max                      = max_r cumsum[r][255] (= row sum)
__global__ __launch_bounds__(256) void curve_fused_kernel(
    const float* __restrict__ img,
    const float* __restrict__ rr, const float* __restrict__ gr,
    const float* __restrict__ br, float* __restrict__ out)
{
    __shared__ float srow[NUM_BINS];   // own row: sigmoid, then its cumsum
    __shared__ float lut[NUM_BINS];
    __shared__ float wmax_s[4], wmin_s[4];
    __shared__ float s_mn, s_inv;

    const int plane = blockIdx.y;      // b*3 + c
    const int b = plane / 3;
    const int c = plane - 3 * b;
    const float* __restrict__ src = (c == 0) ? rr : (c == 1) ? gr : br;

    const int t = threadIdx.x;
    const int wave = t >> 6, lane = t & 63;

    // 1) own-row sigmoid into LDS
    srow[t] = sigmoidf_(src[b * NUM_BINS + t]);

    // 2) global min/max ingredients: each wave handles 4 rows.
    //    row sum via 64-lane xor-reduce; bin-0 sigmoid for the min.
    float wmax = -1e30f, wmin = 1e30f;
    for (int r = wave; r < BATCH; r += 4) {
        const float* __restrict__ row = src + r * NUM_BINS;
        const float s0 = sigmoidf_(row[lane]);
        const float s1 = sigmoidf_(row[lane + 64]);
        const float s2 = sigmoidf_(row[lane + 128]);
        const float s3 = sigmoidf_(row[lane + 192]);
        if (lane == 0) wmin = fminf(wmin, s0);
        float sum = (s0 + s1) + (s2 + s3);
        #pragma unroll
        for (int d = 32; d > 0; d >>= 1) sum += __shfl_xor(sum, d, 64);
        wmax = fmaxf(wmax, sum);
    }
    if (lane == 0) { wmax_s[wave] = wmax; wmin_s[wave] = wmin; }
    __syncthreads();

    // 3) wave 0: inclusive scan of own row (lane owns 4 consecutive bins)
    if (wave == 0) {
        const float v0 = srow[lane * 4 + 0];
        const float v1 = srow[lane * 4 + 1];
        const float v2 = srow[lane * 4 + 2];
        const float v3 = srow[lane * 4 + 3];
        const float p1 = v0 + v1, p2 = p1 + v2, p3 = p2 + v3;
        float sum = p3;
        #pragma unroll
        for (int d = 1; d < 64; d <<= 1) {
            const float o = __shfl_up(sum, d, 64);
            if (lane >= d) sum += o;
        }
        const float off = sum - p3;
        srow[lane * 4 + 0] = off + v0;
        srow[lane * 4 + 1] = off + p1;
        srow[lane * 4 + 2] = off + p2;
        srow[lane * 4 + 3] = off + p3;
        if (lane == 0) {
            const float mx = fmaxf(fmaxf(wmax_s[0], wmax_s[1]),
                                   fmaxf(wmax_s[2], wmax_s[3]));
            const float mn = fminf(fminf(wmin_s[0], wmin_s[1]),
                                   fminf(wmin_s[2], wmin_s[3]));
            s_mn = mn;
            s_inv = 1.0f / (mx - mn);
        }
    }
    __syncthreads();
    lut[t] = (srow[t] - s_mn) * s_inv;
    __syncthreads();

    // 4) stream the plane slice: 8 x float4 per thread, NT stores.
    const size_t planeOff4 = (size_t)plane * VEC_PER_PLANE;
    const f32x4* __restrict__ sp = (const f32x4*)img + planeOff4;
    f32x4* __restrict__ dp = (f32x4*)out + planeOff4;
    const int base = blockIdx.x * (256 * F4_PER_THREAD) + t;
    #pragma unroll
    for (int k = 0; k < F4_PER_THREAD; ++k) {
        const int i = base + k * 256;
        const f32x4 v = sp[i];
        f32x4 o;
        o.x = lut[(int)fminf(fmaxf(v.x * 255.0f, 0.0f), 255.0f)];
        o.y = lut[(int)fminf(fmaxf(v.y * 255.0f, 0.0f), 255.0f)];
        o.z = lut[(int)fminf(fmaxf(v.z * 255.0f, 0.0f), 255.0f)];
        o.w = lut[(int)fminf(fmaxf(v.w * 255.0f, 0.0f), 255.0f)];
        __builtin_nontemporal_store(o, dp + i);
    }
}

extern "C" void kernel_launch(void* const* d_in, const int* in_sizes, int n_in,
                              void* d_out, int out_size, void* d_ws, size_t ws_size,
                              hipStream_t stream) {
    const float* img = (const float*)d_in[0];
    const float* rr  = (const float*)d_in[1];
    const float* gr  = (const float*)d_in[2];
    const float* br  = (const float*)d_in[3];
    float* out = (float*)d_out;

    curve_fused_kernel<<<dim3(BLOCKS_PER_PLANE, 48), dim3(256), 0, stream>>>(
        img, rr, gr, br, out);
}